// Round 12
// baseline (83728.564 us; speedup 1.0000x reference)
//
#include <hip/hip_runtime.h>
#include <hip/hip_bf16.h>
#include <math.h>

__device__ __forceinline__ float geluf(float x) {
    return 0.5f * x * (1.0f + erff(x * 0.70710678118654752f));
}
#define MAPNEGINF 0x007FFFFFu
__device__ __forceinline__ float funmap(unsigned m) {
    return __uint_as_float((m & 0x80000000u) ? (m ^ 0x80000000u) : ~m);
}
__device__ __forceinline__ unsigned fmap(float f) {
    unsigned u = __float_as_uint(f);
    return ((int)u < 0) ? ~u : (u | 0x80000000u);
}
__device__ __forceinline__ float wred64(float v) {
#pragma unroll
    for (int m = 1; m < 64; m <<= 1) v += __shfl_xor(v, m);
    return v;
}
__device__ __forceinline__ unsigned short bf16r(float f) {
    unsigned u = __float_as_uint(f);
    u += 0x7fffu + ((u >> 16) & 1u);
    return (unsigned short)(u >> 16);
}

// ---------------- GEMM tile helpers ----------------
__device__ __forceinline__ void stage_wq(float* Ws, const float* __restrict__ src, int t) {
#pragma unroll
    for (int it = 0; it < 4; ++it) {
        const int idx = it * 1024 + (t << 2);
        *(float4*)(Ws + idx) = *(const float4*)(src + idx);
    }
}

__device__ __forceinline__ void kloop_q(const float* As, const float* Ws, float (&acc)[4][8],
                                        const int r0, const int ogc, const int kb) {
#pragma unroll
    for (int kk = 0; kk < 32; kk += 4) {
        const float4 a0 = *(const float4*)(As + (r0 + 0) * 132 + kb + kk);
        const float4 a1 = *(const float4*)(As + (r0 + 1) * 132 + kb + kk);
        const float4 a2 = *(const float4*)(As + (r0 + 2) * 132 + kb + kk);
        const float4 a3 = *(const float4*)(As + (r0 + 3) * 132 + kb + kk);
#define MAD8(R, AV)                                                                     \
    {                                                                                   \
        acc[R][0] += (AV)*wA.x; acc[R][1] += (AV)*wA.y; acc[R][2] += (AV)*wA.z;         \
        acc[R][3] += (AV)*wA.w; acc[R][4] += (AV)*wB.x; acc[R][5] += (AV)*wB.y;         \
        acc[R][6] += (AV)*wB.z; acc[R][7] += (AV)*wB.w;                                 \
    }
#define KSTEP(J, C)                                                                     \
    {                                                                                   \
        const float4 wA = *(const float4*)(Ws + (kk + (J)) * 128 + ogc);                \
        const float4 wB = *(const float4*)(Ws + (kk + (J)) * 128 + 64 + ogc);           \
        MAD8(0, a0.C) MAD8(1, a1.C) MAD8(2, a2.C) MAD8(3, a3.C)                         \
    }
        KSTEP(0, x) KSTEP(1, y) KSTEP(2, z) KSTEP(3, w)
#undef KSTEP
#undef MAD8
    }
}

// ---------------- misc ----------------
__global__ void k_zero(unsigned* __restrict__ p, int n) {
    const int i = blockIdx.x * 256 + threadIdx.x;
    if (i < n) p[i] = 0u;
}

__global__ void k_copyu(const unsigned* __restrict__ a, const unsigned* __restrict__ b,
                        unsigned* __restrict__ ac, unsigned* __restrict__ bc, int n) {
    const int i = blockIdx.x * 256 + threadIdx.x;
    if (i < n) {
        ac[i] = a[i];
        bc[i] = b[i];
    }
}

// ---------------- CSR build ----------------
__global__ void k_count(const int* __restrict__ ei, unsigned* __restrict__ deg, int E) {
    const int e = blockIdx.x * 256 + threadIdx.x;
    if (e < E) atomicAdd(deg + ei[E + e], 1u);
}

__global__ void k_scan1(const unsigned* __restrict__ deg, unsigned* __restrict__ excl,
                        unsigned* __restrict__ bsum, int n) {
    __shared__ unsigned sh[256];
    const int t = threadIdx.x;
    const int base = blockIdx.x * 1024 + t * 4;
    unsigned v0 = (base + 0 < n) ? deg[base + 0] : 0u;
    unsigned v1 = (base + 1 < n) ? deg[base + 1] : 0u;
    unsigned v2 = (base + 2 < n) ? deg[base + 2] : 0u;
    unsigned v3 = (base + 3 < n) ? deg[base + 3] : 0u;
    const unsigned s = v0 + v1 + v2 + v3;
    sh[t] = s;
    __syncthreads();
    for (int off = 1; off < 256; off <<= 1) {
        unsigned x = 0;
        if (t >= off) x = sh[t - off];
        __syncthreads();
        if (t >= off) sh[t] += x;
        __syncthreads();
    }
    const unsigned ebase = sh[t] - s;
    if (base + 0 < n) excl[base + 0] = ebase;
    if (base + 1 < n) excl[base + 1] = ebase + v0;
    if (base + 2 < n) excl[base + 2] = ebase + v0 + v1;
    if (base + 3 < n) excl[base + 3] = ebase + v0 + v1 + v2;
    if (t == 255) bsum[blockIdx.x] = sh[255];
}

__global__ void k_scan2(unsigned* __restrict__ bsum, int nb) {
    __shared__ unsigned sh[256];
    const int t = threadIdx.x;
    const unsigned v = (t < nb) ? bsum[t] : 0u;
    sh[t] = v;
    __syncthreads();
    for (int off = 1; off < 256; off <<= 1) {
        unsigned x = 0;
        if (t >= off) x = sh[t - off];
        __syncthreads();
        if (t >= off) sh[t] += x;
        __syncthreads();
    }
    if (t < nb) bsum[t] = sh[t] - v;  // exclusive
}

__global__ void k_scan3(unsigned* __restrict__ excl, const unsigned* __restrict__ bsum, int n) {
    const int t = threadIdx.x;
    const int base = blockIdx.x * 1024 + t * 4;
    const unsigned add = bsum[blockIdx.x];
#pragma unroll
    for (int j = 0; j < 4; ++j)
        if (base + j < n) excl[base + j] += add;
}

__global__ void k_scatter(const int* __restrict__ ei, unsigned* __restrict__ cursor,
                          int* __restrict__ esrc, int* __restrict__ edst, int E) {
    const int e = blockIdx.x * 256 + threadIdx.x;
    if (e < E) {
        const int s = ei[e];
        const int d = ei[E + e];
        const unsigned pos = atomicAdd(cursor + d, 1u);
        esrc[pos] = s;
        edst[pos] = d;
    }
}

// ---------------- fused input net ----------------
__global__ void k_in(const float* __restrict__ x, const float* __restrict__ W1,
                     const float* __restrict__ b1, const float* __restrict__ g1,
                     const float* __restrict__ bn1, const float* __restrict__ W2,
                     const float* __restrict__ b2, const float* __restrict__ g2,
                     const float* __restrict__ bn2, float* __restrict__ C, int n) {
    __shared__ float As[64 * 132];
    __shared__ float Ws[4096];
    __shared__ float W1s[512];
    const int t = threadIdx.x;
    const int n0 = blockIdx.x * 64;
    if (t < 128) {
        W1s[t] = W1[t];
        W1s[128 + t] = W1[128 + t];
        W1s[256 + t] = W1[256 + t];
        W1s[384 + t] = W1[384 + t];
    }
    __syncthreads();
    {
        const int r = t >> 2, c0 = (t & 3) << 5;
        const int row = n0 + r;
        float4 xv = make_float4(0.f, 0.f, 0.f, 0.f);
        if (row < n) xv = *(const float4*)(x + (size_t)row * 4);
        float hv[32];
        float s = 0.f, q = 0.f;
#pragma unroll
        for (int j = 0; j < 32; ++j) {
            const int c = c0 + j;
            const float z = b1[c] + xv.x * W1s[c] + xv.y * W1s[128 + c] +
                            xv.z * W1s[256 + c] + xv.w * W1s[384 + c];
            hv[j] = z;
            s += z;
            q += z * z;
        }
        s += __shfl_xor(s, 1); s += __shfl_xor(s, 2);
        q += __shfl_xor(q, 1); q += __shfl_xor(q, 2);
        const float mean = s * 0.0078125f;
        const float var = q * 0.0078125f - mean * mean;
        const float rs = rsqrtf(var + 1e-5f);
#pragma unroll
        for (int j = 0; j < 32; ++j) {
            const int c = c0 + j;
            As[r * 132 + c] = geluf((hv[j] - mean) * rs * g1[c] + bn1[c]);
        }
    }
    float acc[4][8];
#pragma unroll
    for (int r = 0; r < 4; ++r)
#pragma unroll
        for (int o = 0; o < 8; ++o) acc[r][o] = 0.f;
    const int og = t & 15, eg = t >> 4;
    const int ogc = og << 2, r0 = eg << 2;
#pragma unroll
    for (int q4 = 0; q4 < 4; ++q4) {
        stage_wq(Ws, W2 + q4 * 4096, t);
        __syncthreads();
        kloop_q(As, Ws, acc, r0, ogc, q4 * 32);
        __syncthreads();
    }
    const float4 bA = *(const float4*)(b2 + ogc);
    const float4 bB = *(const float4*)(b2 + 64 + ogc);
    const float4 gA = *(const float4*)(g2 + ogc);
    const float4 gB = *(const float4*)(g2 + 64 + ogc);
    const float4 lA = *(const float4*)(bn2 + ogc);
    const float4 lB = *(const float4*)(bn2 + 64 + ogc);
#pragma unroll
    for (int r = 0; r < 4; ++r) {
        float v[8];
        v[0] = acc[r][0] + bA.x; v[1] = acc[r][1] + bA.y;
        v[2] = acc[r][2] + bA.z; v[3] = acc[r][3] + bA.w;
        v[4] = acc[r][4] + bB.x; v[5] = acc[r][5] + bB.y;
        v[6] = acc[r][6] + bB.z; v[7] = acc[r][7] + bB.w;
        float s = 0.f, q = 0.f;
#pragma unroll
        for (int o = 0; o < 8; ++o) { s += v[o]; q += v[o] * v[o]; }
#pragma unroll
        for (int m = 1; m < 16; m <<= 1) { s += __shfl_xor(s, m); q += __shfl_xor(q, m); }
        const float mean = s * 0.0078125f;
        const float var = q * 0.0078125f - mean * mean;
        const float rs = rsqrtf(var + 1e-5f);
        const int row = n0 + r0 + r;
        if (row < n) {
            *(float4*)(C + (size_t)row * 128 + ogc) = make_float4(
                (v[0] - mean) * rs * gA.x + lA.x, (v[1] - mean) * rs * gA.y + lA.y,
                (v[2] - mean) * rs * gA.z + lA.z, (v[3] - mean) * rs * gA.w + lA.w);
            *(float4*)(C + (size_t)row * 128 + 64 + ogc) = make_float4(
                (v[4] - mean) * rs * gB.x + lB.x, (v[5] - mean) * rs * gB.y + lB.y,
                (v[6] - mean) * rs * gB.z + lB.z, (v[7] - mean) * rs * gB.w + lB.w);
        }
    }
}

// ---------------- P & Q (+ fused residual update) ----------------
__global__ void k_pq(float* __restrict__ xcur, const float* __restrict__ upd,
                     const float* __restrict__ pbl, const float* __restrict__ g,
                     const float* __restrict__ b, const float* __restrict__ cW1,
                     const float* __restrict__ cb1, unsigned short* __restrict__ P,
                     unsigned short* __restrict__ Q, int n) {
    __shared__ float As[64 * 132];
    __shared__ float Ws[4096];
    __shared__ float sg[128], sb[128];
    const int t = threadIdx.x;
    const int n0 = blockIdx.x * 64;
    if (t < 128) { sg[t] = g[t]; sb[t] = b[t]; }
    __syncthreads();
    {
        const int r = t >> 2, c0 = (t & 3) << 5;
        const int row = n0 + r;
        const bool ok = row < n;
        float4 v4[8];
        float s = 0.f, q = 0.f;
        if (ok) {
#pragma unroll
            for (int j = 0; j < 8; ++j) {
                const int c = c0 + (j << 2);
                float4 xv = *(const float4*)(xcur + (size_t)row * 128 + c);
                if (upd) {
                    const float4 u = *(const float4*)(upd + (size_t)row * 128 + c);
                    const float4 pv = *(const float4*)(pbl + c);
                    xv = make_float4(xv.x + u.x + pv.x, xv.y + u.y + pv.y, xv.z + u.z + pv.z,
                                     xv.w + u.w + pv.w);
                    *(float4*)(xcur + (size_t)row * 128 + c) = xv;
                }
                v4[j] = xv;
                s += xv.x + xv.y + xv.z + xv.w;
                q += xv.x * xv.x + xv.y * xv.y + xv.z * xv.z + xv.w * xv.w;
            }
        } else {
#pragma unroll
            for (int j = 0; j < 8; ++j) v4[j] = make_float4(0.f, 0.f, 0.f, 0.f);
        }
        s += __shfl_xor(s, 1); s += __shfl_xor(s, 2);
        q += __shfl_xor(q, 1); q += __shfl_xor(q, 2);
        const float mean = s * 0.0078125f;
        const float var = q * 0.0078125f - mean * mean;
        const float rs = rsqrtf(var + 1e-5f);
#pragma unroll
        for (int j = 0; j < 8; ++j) {
            const int c = c0 + (j << 2);
            As[r * 132 + c + 0] = (v4[j].x - mean) * rs * sg[c + 0] + sb[c + 0];
            As[r * 132 + c + 1] = (v4[j].y - mean) * rs * sg[c + 1] + sb[c + 1];
            As[r * 132 + c + 2] = (v4[j].z - mean) * rs * sg[c + 2] + sb[c + 2];
            As[r * 132 + c + 3] = (v4[j].w - mean) * rs * sg[c + 3] + sb[c + 3];
        }
    }
    float accP[4][8], accQ[4][8];
#pragma unroll
    for (int r = 0; r < 4; ++r)
#pragma unroll
        for (int o = 0; o < 8; ++o) { accP[r][o] = 0.f; accQ[r][o] = 0.f; }
    const int og = t & 15, eg = t >> 4;
    const int ogc = og << 2, r0 = eg << 2;
#pragma unroll
    for (int q4 = 0; q4 < 4; ++q4) {
        stage_wq(Ws, cW1 + q4 * 4096, t);
        __syncthreads();
        kloop_q(As, Ws, accP, r0, ogc, q4 * 32);
        __syncthreads();
        stage_wq(Ws, cW1 + 16384 + q4 * 4096, t);
        __syncthreads();
        kloop_q(As, Ws, accQ, r0, ogc, q4 * 32);
        __syncthreads();
    }
    const float4 bA = *(const float4*)(cb1 + ogc);
    const float4 bB = *(const float4*)(cb1 + 64 + ogc);
#pragma unroll
    for (int r = 0; r < 4; ++r) {
        const int row = n0 + r0 + r;
        if (row < n) {
            ushort4 p0, p1, q0, q1;
            p0.x = bf16r(accP[r][0] - accQ[r][0] + bA.x);
            p0.y = bf16r(accP[r][1] - accQ[r][1] + bA.y);
            p0.z = bf16r(accP[r][2] - accQ[r][2] + bA.z);
            p0.w = bf16r(accP[r][3] - accQ[r][3] + bA.w);
            p1.x = bf16r(accP[r][4] - accQ[r][4] + bB.x);
            p1.y = bf16r(accP[r][5] - accQ[r][5] + bB.y);
            p1.z = bf16r(accP[r][6] - accQ[r][6] + bB.z);
            p1.w = bf16r(accP[r][7] - accQ[r][7] + bB.w);
            q0.x = bf16r(accQ[r][0]); q0.y = bf16r(accQ[r][1]);
            q0.z = bf16r(accQ[r][2]); q0.w = bf16r(accQ[r][3]);
            q1.x = bf16r(accQ[r][4]); q1.y = bf16r(accQ[r][5]);
            q1.z = bf16r(accQ[r][6]); q1.w = bf16r(accQ[r][7]);
            *(ushort4*)(P + (size_t)row * 128 + ogc) = p0;
            *(ushort4*)(P + (size_t)row * 128 + 64 + ogc) = p1;
            *(ushort4*)(Q + (size_t)row * 128 + ogc) = q0;
            *(ushort4*)(Q + (size_t)row * 128 + 64 + ogc) = q1;
        }
    }
}

// ---------------- fused edge conv + per-run pW matvec -> upd (P run-cache) ----------------
__global__ __launch_bounds__(256, 2) void k_edge(
    const unsigned short* __restrict__ P, const unsigned short* __restrict__ Q,
    const int* __restrict__ esrc, const int* __restrict__ edst, const float* __restrict__ W2,
    const float* __restrict__ g1, const float* __restrict__ b1, const float* __restrict__ cb2,
    const float* __restrict__ g2, const float* __restrict__ b2,
    const unsigned* __restrict__ rowend, const unsigned* __restrict__ degc,
    const float* __restrict__ pW, float* __restrict__ upd, float* __restrict__ recmax,
    float* __restrict__ recsum, int* __restrict__ recid, int E) {
    __shared__ float Us[64 * 132];
    __shared__ float Ws[4096];
    __shared__ unsigned Pcu[64 * 64];
    __shared__ int sdst[64], ssrc[64], sdg[64];
    __shared__ unsigned char srid[64], sfirst[64];
    __shared__ float scb2[128], sg2[128], sb2[128];
    __shared__ float smx[128], ssm[128], spart[256];
    const int t = threadIdx.x;
    const int base = blockIdx.x * 512;
    if (t >= 128) {
        const int d = t - 128;
        scb2[d] = cb2[d];
        sg2[d] = g2[d];
        sb2[d] = b2[d];
    }
    const int lane = t & 63, wave = t >> 6;
    const int d0 = lane << 1;
    const float g1a = g1[d0], g1b = g1[d0 + 1], b1a = b1[d0], b1b = b1[d0 + 1];
    const int og = t & 15, eg = t >> 4;
    const int ogc = og << 2, r0 = eg << 2;
    int cur = -1, istart = 0;
    float vmax = -INFINITY, vsum = 0.f;
    int id0 = -1, id1 = -1;

    auto flushrun = [&](int iend) {
        const unsigned re = rowend[cur];
        const unsigned dg = degc[cur];
        const unsigned rs0 = re - dg;
        const unsigned ps = (unsigned)(base + istart), pe = (unsigned)(base + iend);
        if (ps == rs0 && pe == re) {
            if (t < 128) {
                smx[t] = vmax;
                ssm[t] = vsum / (float)dg;
            }
            __syncthreads();
            {
                const int d = t & 127;
                const float* wc = pW + ((t >> 7) ? 16384 : 0) + d;
                const float* sv = (t >> 7) ? ssm : smx;
                float a = 0.f;
#pragma unroll 8
                for (int k = 0; k < 128; ++k) a += sv[k] * wc[(size_t)k << 7];
                spart[t] = a;
            }
            __syncthreads();
            if (t < 128) upd[(size_t)cur * 128 + t] = spart[t] + spart[t + 128];
        } else {
            const int slot = (istart == 0) ? 0 : 1;
            if (t < 128) {
                const size_t ro = (size_t)(2 * blockIdx.x + slot) * 128 + t;
                recmax[ro] = vmax;
                recsum[ro] = vsum;
            }
            if (slot == 0) id0 = cur; else id1 = cur;
        }
    };

    for (int s8 = 0; s8 < 8; ++s8) {
        const int sb = base + s8 * 64;
        __syncthreads();
        if (t < 64) {
            const int idx = sb + t;
            const int ci = idx < E ? idx : (E - 1);
            ssrc[t] = esrc[ci];
            const int d = edst[ci];
            sdg[t] = d;
            sdst[t] = (idx < E) ? d : -1;
        }
        __syncthreads();
        if (t < 64) {
            const int first = (t == 0) ? 1 : (sdg[t] != sdg[t - 1]);
            int scanv = first;
#pragma unroll
            for (int o = 1; o < 64; o <<= 1) {
                const int up = __shfl_up(scanv, o);
                if (lane >= o) scanv += up;
            }
            sfirst[t] = (unsigned char)first;
            srid[t] = (unsigned char)(scanv - 1);
        }
        __syncthreads();
        // A1: Q gathers to regs; distinct P rows -> LDS cache
        unsigned quv[16];
#pragma unroll 4
        for (int p = 0; p < 16; ++p) {
            const int i = (p << 2) + wave;
            quv[p] = *(const unsigned*)(Q + ((size_t)ssrc[i] << 7) + d0);
            if (sfirst[i]) {
                Pcu[(int)srid[i] * 64 + lane] =
                    *(const unsigned*)(P + ((size_t)sdg[i] << 7) + d0);
            }
        }
        __syncthreads();
        // A2: U rows = GELU(LN(P+Q))
#pragma unroll 4
        for (int p = 0; p < 16; ++p) {
            const int i = (p << 2) + wave;
            const unsigned pu = Pcu[(int)srid[i] * 64 + lane];
            const unsigned qu = quv[p];
            const float x0 = __uint_as_float(pu << 16) + __uint_as_float(qu << 16);
            const float x1 =
                __uint_as_float(pu & 0xffff0000u) + __uint_as_float(qu & 0xffff0000u);
            const float s = wred64(x0 + x1);
            const float q = wred64(x0 * x0 + x1 * x1);
            const float mean = s * 0.0078125f;
            const float var = q * 0.0078125f - mean * mean;
            const float rs = rsqrtf(var + 1e-5f);
            const float y0 = geluf((x0 - mean) * rs * g1a + b1a);
            const float y1 = geluf((x1 - mean) * rs * g1b + b1b);
            *(float2*)(Us + i * 132 + d0) = make_float2(y0, y1);
        }
        // B: GEMM
        float acc[4][8];
#pragma unroll
        for (int r = 0; r < 4; ++r)
#pragma unroll
            for (int o = 0; o < 8; ++o) acc[r][o] = 0.f;
#pragma unroll
        for (int q4 = 0; q4 < 4; ++q4) {
            stage_wq(Ws, W2 + q4 * 4096, t);
            __syncthreads();
            kloop_q(Us, Ws, acc, r0, ogc, q4 * 32);
            __syncthreads();
        }
#pragma unroll
        for (int r = 0; r < 4; ++r) {
            float v[8];
            float s = 0.f, q = 0.f;
#pragma unroll
            for (int o = 0; o < 8; ++o) {
                const int col = (o < 4) ? (ogc + o) : (64 + ogc + o - 4);
                v[o] = acc[r][o] + scb2[col];
                s += v[o];
                q += v[o] * v[o];
            }
#pragma unroll
            for (int m = 1; m < 16; m <<= 1) { s += __shfl_xor(s, m); q += __shfl_xor(q, m); }
            const float mean = s * 0.0078125f;
            const float var = q * 0.0078125f - mean * mean;
            const float rs = rsqrtf(var + 1e-5f);
#pragma unroll
            for (int o = 0; o < 8; ++o) {
                const int col = (o < 4) ? (ogc + o) : (64 + ogc + o - 4);
                v[o] = geluf((v[o] - mean) * rs * sg2[col] + sb2[col]);
            }
            *(float4*)(Us + (r0 + r) * 132 + ogc) = make_float4(v[0], v[1], v[2], v[3]);
            *(float4*)(Us + (r0 + r) * 132 + 64 + ogc) = make_float4(v[4], v[5], v[6], v[7]);
        }
        __syncthreads();
        for (int i = 0; i < 64; ++i) {
            const int dn = sdst[i];
            const int gi = s8 * 64 + i;
            if (dn != cur) {
                if (cur >= 0) flushrun(gi);
                cur = dn;
                istart = gi;
                vmax = -INFINITY;
                vsum = 0.f;
            }
            if (dn >= 0 && t < 128) {
                const float v = Us[i * 132 + t];
                vmax = fmaxf(vmax, v);
                vsum += v;
            }
        }
    }
    if (cur >= 0) flushrun(min(512, E - base));
    if (t == 0) {
        recid[2 * blockIdx.x] = id0;
        recid[2 * blockIdx.x + 1] = id1;
    }
}

// ---------------- merge boundary records + empty nodes -> upd ----------------
__global__ void k_merge2(const unsigned* __restrict__ rowend, const unsigned* __restrict__ degc,
                         const float* __restrict__ recmax, const float* __restrict__ recsum,
                         const int* __restrict__ recid, const float* __restrict__ pW,
                         float* __restrict__ upd, int n) {
    __shared__ float sm[128], ss[128];
    const int node = blockIdx.x;
    const int d = threadIdx.x;
    if (node >= n) return;
    const unsigned dg = degc[node];
    if (dg == 0u) {
        upd[(size_t)node * 128 + d] = 0.f;
        return;
    }
    const unsigned re = rowend[node], rs = re - dg;
    const int b0 = rs >> 9, b1 = (re - 1) >> 9;
    if (b0 == b1) return;
    float m = -INFINITY, s = 0.f;
    for (int b = b0; b <= b1; ++b) {
#pragma unroll
        for (int sl = 0; sl < 2; ++sl) {
            if (recid[2 * b + sl] == node) {
                const size_t ro = (size_t)(2 * b + sl) * 128 + d;
                m = fmaxf(m, recmax[ro]);
                s += recsum[ro];
            }
        }
    }
    sm[d] = m;
    ss[d] = s / (float)dg;
    __syncthreads();
    float a = 0.f;
#pragma unroll 8
    for (int k = 0; k < 128; ++k)
        a += sm[k] * pW[(size_t)k * 128 + d] + ss[k] * pW[(size_t)(128 + k) * 128 + d];
    upd[(size_t)node * 128 + d] = a;
}

// ---------------- fused final: x=xcur+upd+pb -> LN -> graph pooling ----------------
__global__ void k_lnpool(const float* __restrict__ xcur, const float* __restrict__ upd,
                         const float* __restrict__ pbl, const float* __restrict__ g,
                         const float* __restrict__ b, const int* __restrict__ batch,
                         unsigned* __restrict__ gmax, float* __restrict__ gsum,
                         unsigned* __restrict__ gcount, int n) {
    __shared__ float Ys[64 * 132];
    __shared__ int sbt[64];
    const int t = threadIdx.x;
    const int n0 = blockIdx.x * 64;
    if (t < 64) {
        const int node = n0 + t;
        sbt[t] = (node < n) ? batch[node] : -1;
    }
    {
        const int r = t >> 2, c0 = (t & 3) << 5;
        const int row = n0 + r;
        const bool ok = row < n;
        float4 v4[8];
        float s = 0.f, q = 0.f;
        if (ok) {
#pragma unroll
            for (int j = 0; j < 8; ++j) {
                const int c = c0 + (j << 2);
                const float4 xv = *(const float4*)(xcur + (size_t)row * 128 + c);
                const float4 u = *(const float4*)(upd + (size_t)row * 128 + c);
                const float4 pv = *(const float4*)(pbl + c);
                v4[j] = make_float4(xv.x + u.x + pv.x, xv.y + u.y + pv.y, xv.z + u.z + pv.z,
                                    xv.w + u.w + pv.w);
                s += v4[j].x + v4[j].y + v4[j].z + v4[j].w;
                q += v4[j].x * v4[j].x + v4[j].y * v4[j].y + v4[j].z * v4[j].z +
                     v4[j].w * v4[j].w;
            }
        } else {
#pragma unroll
            for (int j = 0; j < 8; ++j) v4[j] = make_float4(0.f, 0.f, 0.f, 0.f);
        }
        s += __shfl_xor(s, 1); s += __shfl_xor(s, 2);
        q += __shfl_xor(q, 1); q += __shfl_xor(q, 2);
        const float mean = s * 0.0078125f;
        const float var = q * 0.0078125f - mean * mean;
        const float rs = rsqrtf(var + 1e-5f);
#pragma unroll
        for (int j = 0; j < 8; ++j) {
            const int c = c0 + (j << 2);
            Ys[r * 132 + c + 0] = (v4[j].x - mean) * rs * g[c + 0] + b[c + 0];
            Ys[r * 132 + c + 1] = (v4[j].y - mean) * rs * g[c + 1] + b[c + 1];
            Ys[r * 132 + c + 2] = (v4[j].z - mean) * rs * g[c + 2] + b[c + 2];
            Ys[r * 132 + c + 3] = (v4[j].w - mean) * rs * g[c + 3] + b[c + 3];
        }
    }
    __syncthreads();
    if (t < 128) {
        int curg = -1;
        float vmax = -INFINITY, vsum = 0.f;
        unsigned cnt = 0;
        for (int i = 0; i < 64; ++i) {
            const int gid = sbt[i];
            if (gid != curg) {
                if (curg >= 0) {
                    atomicMax(gmax + (size_t)curg * 128 + t, fmap(vmax));
                    atomicAdd(gsum + (size_t)curg * 128 + t, vsum);
                    if (t == 0) atomicAdd(gcount + curg, cnt);
                }
                curg = gid;
                vmax = -INFINITY;
                vsum = 0.f;
                cnt = 0;
            }
            if (gid >= 0) {
                const float v = Ys[i * 132 + t];
                vmax = fmaxf(vmax, v);
                vsum += v;
                cnt++;
            }
        }
        if (curg >= 0) {
            atomicMax(gmax + (size_t)curg * 128 + t, fmap(vmax));
            atomicAdd(gsum + (size_t)curg * 128 + t, vsum);
            if (t == 0) atomicAdd(gcount + curg, cnt);
        }
    }
}

// ---------------- graph pooling (input stage) ----------------
__global__ void k_pool_init(unsigned* __restrict__ gmax1, float* __restrict__ gsum1,
                            unsigned* __restrict__ gcount1, unsigned* __restrict__ gmax2,
                            float* __restrict__ gsum2, unsigned* __restrict__ gcount2, int ng) {
    const int i = blockIdx.x * 256 + threadIdx.x;
    if (i < ng * 128) {
        gmax1[i] = MAPNEGINF;
        gsum1[i] = 0.f;
        gmax2[i] = MAPNEGINF;
        gsum2[i] = 0.f;
    }
    if (i < ng) {
        gcount1[i] = 0u;
        gcount2[i] = 0u;
    }
}

__global__ void k_pool(const float* __restrict__ in, const int* __restrict__ batch,
                       unsigned* __restrict__ gmax, float* __restrict__ gsum,
                       unsigned* __restrict__ gcount, int n) {
    const int t = threadIdx.x;
    if (t >= 128) return;
    const int per = (n + gridDim.x - 1) / gridDim.x;
    const int i0 = blockIdx.x * per;
    const int i1 = min(n, i0 + per);
    if (i0 >= i1) return;
    int cur = batch[i0];
    float vmax = -INFINITY, vsum = 0.f;
    unsigned cnt = 0;
    for (int i = i0; i < i1; ++i) {
        const int g = batch[i];
        if (g != cur) {
            atomicMax(gmax + (size_t)cur * 128 + t, fmap(vmax));
            atomicAdd(gsum + (size_t)cur * 128 + t, vsum);
            if (t == 0) atomicAdd(gcount + cur, cnt);
            cur = g;
            vmax = -INFINITY;
            vsum = 0.f;
            cnt = 0;
        }
        const float v = in[(size_t)i * 128 + t];
        vmax = fmaxf(vmax, v);
        vsum += v;
        cnt++;
    }
    atomicMax(gmax + (size_t)cur * 128 + t, fmap(vmax));
    atomicAdd(gsum + (size_t)cur * 128 + t, vsum);
    if (t == 0) atomicAdd(gcount + cur, cnt);
}

__global__ void k_xp(const unsigned* __restrict__ gmax1, const float* __restrict__ gsum1,
                     const unsigned* __restrict__ gcount1, const unsigned* __restrict__ gmax2,
                     const float* __restrict__ gsum2, const unsigned* __restrict__ gcount2,
                     float* __restrict__ xp) {
    const int g = blockIdx.x, d = threadIdx.x;
    const unsigned c1u = gcount1[g], c2u = gcount2[g];
    const float c1 = (float)(c1u < 1u ? 1u : c1u);
    const float c2 = (float)(c2u < 1u ? 1u : c2u);
    const unsigned m1 = gmax1[g * 128 + d], m2 = gmax2[g * 128 + d];
    xp[g * 512 + d] = (m1 == MAPNEGINF) ? 0.f : funmap(m1);
    xp[g * 512 + 128 + d] = gsum1[g * 128 + d] / c1;
    xp[g * 512 + 256 + d] = (m2 == MAPNEGINF) ? 0.f : funmap(m2);
    xp[g * 512 + 384 + d] = gsum2[g * 128 + d] / c2;
}

// ---------------- knowledge MLP (tiny) ----------------
__global__ __launch_bounds__(64) void k_know(
    const float* __restrict__ xp, const float* __restrict__ kW1, const float* __restrict__ kb1,
    const float* __restrict__ kg1, const float* __restrict__ kbb1, const float* __restrict__ kW2,
    const float* __restrict__ kb2, const float* __restrict__ kg2, const float* __restrict__ kbb2,
    const float* __restrict__ kW3, const float* __restrict__ kb3, const float* __restrict__ kg3,
    const float* __restrict__ kbb3, const float* __restrict__ kW4, const float* __restrict__ kb4,
    float* __restrict__ out) {
    __shared__ float sh[512];
    __shared__ float s3[32];
    const int l = threadIdx.x, g = blockIdx.x;
    const int d0 = l << 1;
    *(float4*)(sh + l * 8) = *(const float4*)(xp + g * 512 + l * 8);
    *(float4*)(sh + l * 8 + 4) = *(const float4*)(xp + g * 512 + l * 8 + 4);
    __syncthreads();
    float a0 = kb1[d0], a1 = kb1[d0 + 1];
    for (int k = 0; k < 512; ++k) {
        const float u = sh[k];
        const float2 w = *(const float2*)(kW1 + k * 128 + d0);
        a0 += u * w.x;
        a1 += u * w.y;
    }
    {
        const float s = wred64(a0 + a1), q = wred64(a0 * a0 + a1 * a1);
        const float mean = s * 0.0078125f, var = q * 0.0078125f - mean * mean;
        const float rs = rsqrtf(var + 1e-5f);
        a0 = geluf((a0 - mean) * rs * kg1[d0] + kbb1[d0]);
        a1 = geluf((a1 - mean) * rs * kg1[d0 + 1] + kbb1[d0 + 1]);
    }
    __syncthreads();
    sh[d0] = a0;
    sh[d0 + 1] = a1;
    __syncthreads();
    float b0v = kb2[d0], b1v = kb2[d0 + 1];
    for (int k = 0; k < 128; ++k) {
        const float u = sh[k];
        const float2 w = *(const float2*)(kW2 + k * 128 + d0);
        b0v += u * w.x;
        b1v += u * w.y;
    }
    {
        const float s = wred64(b0v + b1v), q = wred64(b0v * b0v + b1v * b1v);
        const float mean = s * 0.0078125f, var = q * 0.0078125f - mean * mean;
        const float rs = rsqrtf(var + 1e-5f);
        b0v = geluf((b0v - mean) * rs * kg2[d0] + kbb2[d0]);
        b1v = geluf((b1v - mean) * rs * kg2[d0 + 1] + kbb2[d0 + 1]);
    }
    __syncthreads();
    sh[d0] = b0v;
    sh[d0 + 1] = b1v;
    __syncthreads();
    const int d3 = (l & 15) << 1;
    float c0 = kb3[d3], c1 = kb3[d3 + 1];
    for (int k = 0; k < 128; ++k) {
        const float u = sh[k];
        const float2 w = *(const float2*)(kW3 + k * 32 + d3);
        c0 += u * w.x;
        c1 += u * w.y;
    }
    {
        float s = c0 + c1, q = c0 * c0 + c1 * c1;
#pragma unroll
        for (int m = 1; m < 16; m <<= 1) {
            s += __shfl_xor(s, m);
            q += __shfl_xor(q, m);
        }
        const float mean = s * 0.03125f, var = q * 0.03125f - mean * mean;
        const float rs = rsqrtf(var + 1e-5f);
        c0 = geluf((c0 - mean) * rs * kg3[d3] + kbb3[d3]);
        c1 = geluf((c1 - mean) * rs * kg3[d3 + 1] + kbb3[d3 + 1]);
    }
    if (l < 16) {
        s3[d3] = c0;
        s3[d3 + 1] = c1;
    }
    __syncthreads();
    if (l == 0) {
        float rr = kb4[0];
        for (int k = 0; k < 32; ++k) rr += s3[k] * kW4[k];
        out[g] = rr;
    }
}

// ---------------- host launch ----------------
extern "C" void kernel_launch(void* const* d_in, const int* in_sizes, int n_in, void* d_out,
                              int out_size, void* d_ws, size_t ws_size, hipStream_t stream) {
    const int N = in_sizes[0] / 4;
    const int E = in_sizes[1] / 2;
    const int G = 64;
    const int L = 4;

    const float* x = (const float*)d_in[0];
    const int* ei = (const int*)d_in[1];
    const int* batch = (const int*)d_in[2];
    const float* inW1 = (const float*)d_in[4];
    const float* inb1 = (const float*)d_in[5];
    const float* ing1 = (const float*)d_in[6];
    const float* inbn1 = (const float*)d_in[7];
    const float* inW2 = (const float*)d_in[8];
    const float* inb2 = (const float*)d_in[9];
    const float* ing2 = (const float*)d_in[10];
    const float* inbn2 = (const float*)d_in[11];
    const float* pre_g = (const float*)d_in[12];
    const float* pre_b = (const float*)d_in[13];
    const float* cW1 = (const float*)d_in[14];
    const float* cb1 = (const float*)d_in[15];
    const float* cg1 = (const float*)d_in[16];
    const float* cbb1 = (const float*)d_in[17];
    const float* cW2 = (const float*)d_in[18];
    const float* cb2 = (const float*)d_in[19];
    const float* cg2 = (const float*)d_in[20];
    const float* cbb2 = (const float*)d_in[21];
    const float* pW = (const float*)d_in[22];
    const float* pb = (const float*)d_in[23];
    const float* ag_g = (const float*)d_in[24];
    const float* ag_b = (const float*)d_in[25];
    const float* kW1 = (const float*)d_in[26];
    const float* kb1 = (const float*)d_in[27];
    const float* kg1 = (const float*)d_in[28];
    const float* kbb1 = (const float*)d_in[29];
    const float* kW2 = (const float*)d_in[30];
    const float* kb2 = (const float*)d_in[31];
    const float* kg2 = (const float*)d_in[32];
    const float* kbb2 = (const float*)d_in[33];
    const float* kW3 = (const float*)d_in[34];
    const float* kb3 = (const float*)d_in[35];
    const float* kg3 = (const float*)d_in[36];
    const float* kbb3 = (const float*)d_in[37];
    const float* kW4 = (const float*)d_in[38];
    const float* kb4 = (const float*)d_in[39];
    float* out = (float*)d_out;

    const int nblkE = (E + 511) / 512;

    char* wsb = (char*)d_ws;
    size_t off = 0;
    auto ALC = [&](size_t bytes) {
        void* p = wsb + off;
        off = (off + bytes + 255) & ~(size_t)255;
        return p;
    };
    const size_t NB = (size_t)N * 128 * 4;
    float* xcur = (float*)ALC(NB);
    float* upd = (float*)ALC(NB);
    unsigned short* Pb = (unsigned short*)ALC((size_t)N * 128 * 2);
    unsigned short* Qb = (unsigned short*)ALC((size_t)N * 128 * 2);
    unsigned* deg = (unsigned*)ALC((size_t)N * 4);
    unsigned* cursor = (unsigned*)ALC((size_t)N * 4);
    unsigned* degc = (unsigned*)ALC((size_t)N * 4);
    unsigned* rowend = (unsigned*)ALC((size_t)N * 4);
    unsigned* bsum = (unsigned*)ALC(4096);
    int* esrc = (int*)ALC((size_t)E * 4);
    int* edst = (int*)ALC((size_t)E * 4);
    float* recmax = (float*)ALC((size_t)nblkE * 2 * 128 * 4);
    float* recsum = (float*)ALC((size_t)nblkE * 2 * 128 * 4);
    int* recid = (int*)ALC((size_t)nblkE * 2 * 4);
    unsigned* gmax1 = (unsigned*)ALC((size_t)G * 128 * 4);
    float* gsum1 = (float*)ALC((size_t)G * 128 * 4);
    unsigned* gcount1 = (unsigned*)ALC((size_t)G * 4);
    unsigned* gmax2 = (unsigned*)ALC((size_t)G * 128 * 4);
    float* gsum2 = (float*)ALC((size_t)G * 128 * 4);
    unsigned* gcount2 = (unsigned*)ALC((size_t)G * 4);
    float* xp = (float*)ALC((size_t)G * 512 * 4);

    if (off > ws_size) {
        k_zero<<<(out_size + 255) / 256, 256, 0, stream>>>((unsigned*)d_out, out_size);
        return;
    }

    // --- CSR-style dst-sorted edge arrays ---
    k_zero<<<(N + 255) / 256, 256, 0, stream>>>(deg, N);
    k_count<<<(E + 255) / 256, 256, 0, stream>>>(ei, deg, E);
    const int nb = (N + 1023) / 1024;
    k_scan1<<<nb, 256, 0, stream>>>(deg, cursor, bsum, N);
    k_scan2<<<1, 256, 0, stream>>>(bsum, nb);
    k_scan3<<<nb, 256, 0, stream>>>(cursor, bsum, N);
    k_scatter<<<(E + 255) / 256, 256, 0, stream>>>(ei, cursor, esrc, edst, E);
    k_copyu<<<(N + 255) / 256, 256, 0, stream>>>(deg, cursor, degc, rowend, N);

    // --- input net + first pooling ---
    const int grid64 = (N + 63) / 64;
    k_in<<<grid64, 256, 0, stream>>>(x, inW1, inb1, ing1, inbn1, inW2, inb2, ing2, inbn2, xcur,
                                     N);
    k_pool_init<<<(G * 128 + 255) / 256, 256, 0, stream>>>(gmax1, gsum1, gcount1, gmax2, gsum2,
                                                           gcount2, G);
    k_pool<<<512, 256, 0, stream>>>(xcur, batch, gmax1, gsum1, gcount1, N);

    // --- edge conv layers ---
    for (int l = 0; l < L; ++l) {
        k_pq<<<grid64, 256, 0, stream>>>(xcur, (l == 0) ? (const float*)nullptr : upd,
                                         (l == 0) ? (const float*)nullptr : (pb + (l - 1) * 128),
                                         pre_g + l * 128, pre_b + l * 128,
                                         cW1 + (size_t)l * 32768, cb1 + l * 128, Pb, Qb, N);
        k_edge<<<nblkE, 256, 0, stream>>>(Pb, Qb, esrc, edst, cW2 + (size_t)l * 16384,
                                          cg1 + l * 128, cbb1 + l * 128, cb2 + l * 128,
                                          cg2 + l * 128, cbb2 + l * 128, rowend, degc,
                                          pW + (size_t)l * 32768, upd, recmax, recsum, recid, E);
        k_merge2<<<N, 128, 0, stream>>>(rowend, degc, recmax, recsum, recid,
                                        pW + (size_t)l * 32768, upd, N);
    }

    // --- fused final LN + pooling, then head ---
    k_lnpool<<<grid64, 256, 0, stream>>>(xcur, upd, pb + 3 * 128, ag_g, ag_b, batch, gmax2,
                                         gsum2, gcount2, N);
    k_xp<<<G, 128, 0, stream>>>(gmax1, gsum1, gcount1, gmax2, gsum2, gcount2, xp);
    k_know<<<G, 64, 0, stream>>>(xp, kW1, kb1, kg1, kbb1, kW2, kb2, kg2, kbb2, kW3, kb3, kg3,
                                 kbb3, kW4, kb4, out);
}

// Round 13
// 81849.139 us; speedup vs baseline: 1.0230x; 1.0230x over previous
//
#include <hip/hip_runtime.h>
#include <hip/hip_bf16.h>
#include <math.h>

__device__ __forceinline__ float geluf(float x) {
    return 0.5f * x * (1.0f + erff(x * 0.70710678118654752f));
}
#define MAPNEGINF 0x007FFFFFu
__device__ __forceinline__ float funmap(unsigned m) {
    return __uint_as_float((m & 0x80000000u) ? (m ^ 0x80000000u) : ~m);
}
__device__ __forceinline__ unsigned fmap(float f) {
    unsigned u = __float_as_uint(f);
    return ((int)u < 0) ? ~u : (u | 0x80000000u);
}
__device__ __forceinline__ float wred64(float v) {
#pragma unroll
    for (int m = 1; m < 64; m <<= 1) v += __shfl_xor(v, m);
    return v;
}
__device__ __forceinline__ unsigned short bf16r(float f) {
    unsigned u = __float_as_uint(f);
    u += 0x7fffu + ((u >> 16) & 1u);
    return (unsigned short)(u >> 16);
}

// ---------------- GEMM tile helpers ----------------
__device__ __forceinline__ void stage_wq(float* Ws, const float* __restrict__ src, int t) {
#pragma unroll
    for (int it = 0; it < 4; ++it) {
        const int idx = it * 1024 + (t << 2);
        *(float4*)(Ws + idx) = *(const float4*)(src + idx);
    }
}

__device__ __forceinline__ void kloop_q(const float* As, const float* Ws, float (&acc)[4][8],
                                        const int r0, const int ogc, const int kb) {
#pragma unroll
    for (int kk = 0; kk < 32; kk += 4) {
        const float4 a0 = *(const float4*)(As + (r0 + 0) * 132 + kb + kk);
        const float4 a1 = *(const float4*)(As + (r0 + 1) * 132 + kb + kk);
        const float4 a2 = *(const float4*)(As + (r0 + 2) * 132 + kb + kk);
        const float4 a3 = *(const float4*)(As + (r0 + 3) * 132 + kb + kk);
#define MAD8(R, AV)                                                                     \
    {                                                                                   \
        acc[R][0] += (AV)*wA.x; acc[R][1] += (AV)*wA.y; acc[R][2] += (AV)*wA.z;         \
        acc[R][3] += (AV)*wA.w; acc[R][4] += (AV)*wB.x; acc[R][5] += (AV)*wB.y;         \
        acc[R][6] += (AV)*wB.z; acc[R][7] += (AV)*wB.w;                                 \
    }
#define KSTEP(J, C)                                                                     \
    {                                                                                   \
        const float4 wA = *(const float4*)(Ws + (kk + (J)) * 128 + ogc);                \
        const float4 wB = *(const float4*)(Ws + (kk + (J)) * 128 + 64 + ogc);           \
        MAD8(0, a0.C) MAD8(1, a1.C) MAD8(2, a2.C) MAD8(3, a3.C)                         \
    }
        KSTEP(0, x) KSTEP(1, y) KSTEP(2, z) KSTEP(3, w)
#undef KSTEP
#undef MAD8
    }
}

// ---------------- misc ----------------
__global__ void k_zero(unsigned* __restrict__ p, int n) {
    const int i = blockIdx.x * 256 + threadIdx.x;
    if (i < n) p[i] = 0u;
}

__global__ void k_copyu(const unsigned* __restrict__ a, const unsigned* __restrict__ b,
                        unsigned* __restrict__ ac, unsigned* __restrict__ bc, int n) {
    const int i = blockIdx.x * 256 + threadIdx.x;
    if (i < n) {
        ac[i] = a[i];
        bc[i] = b[i];
    }
}

// ---------------- CSR build ----------------
__global__ void k_count(const int* __restrict__ ei, unsigned* __restrict__ deg, int E) {
    const int e = blockIdx.x * 256 + threadIdx.x;
    if (e < E) atomicAdd(deg + ei[E + e], 1u);
}

__global__ void k_scan1(const unsigned* __restrict__ deg, unsigned* __restrict__ excl,
                        unsigned* __restrict__ bsum, int n) {
    __shared__ unsigned sh[256];
    const int t = threadIdx.x;
    const int base = blockIdx.x * 1024 + t * 4;
    unsigned v0 = (base + 0 < n) ? deg[base + 0] : 0u;
    unsigned v1 = (base + 1 < n) ? deg[base + 1] : 0u;
    unsigned v2 = (base + 2 < n) ? deg[base + 2] : 0u;
    unsigned v3 = (base + 3 < n) ? deg[base + 3] : 0u;
    const unsigned s = v0 + v1 + v2 + v3;
    sh[t] = s;
    __syncthreads();
    for (int off = 1; off < 256; off <<= 1) {
        unsigned x = 0;
        if (t >= off) x = sh[t - off];
        __syncthreads();
        if (t >= off) sh[t] += x;
        __syncthreads();
    }
    const unsigned ebase = sh[t] - s;
    if (base + 0 < n) excl[base + 0] = ebase;
    if (base + 1 < n) excl[base + 1] = ebase + v0;
    if (base + 2 < n) excl[base + 2] = ebase + v0 + v1;
    if (base + 3 < n) excl[base + 3] = ebase + v0 + v1 + v2;
    if (t == 255) bsum[blockIdx.x] = sh[255];
}

__global__ void k_scan2(unsigned* __restrict__ bsum, int nb) {
    __shared__ unsigned sh[256];
    const int t = threadIdx.x;
    const unsigned v = (t < nb) ? bsum[t] : 0u;
    sh[t] = v;
    __syncthreads();
    for (int off = 1; off < 256; off <<= 1) {
        unsigned x = 0;
        if (t >= off) x = sh[t - off];
        __syncthreads();
        if (t >= off) sh[t] += x;
        __syncthreads();
    }
    if (t < nb) bsum[t] = sh[t] - v;  // exclusive
}

__global__ void k_scan3(unsigned* __restrict__ excl, const unsigned* __restrict__ bsum, int n) {
    const int t = threadIdx.x;
    const int base = blockIdx.x * 1024 + t * 4;
    const unsigned add = bsum[blockIdx.x];
#pragma unroll
    for (int j = 0; j < 4; ++j)
        if (base + j < n) excl[base + j] += add;
}

__global__ void k_scatter(const int* __restrict__ ei, unsigned* __restrict__ cursor,
                          int* __restrict__ esrc, int* __restrict__ edst, int E) {
    const int e = blockIdx.x * 256 + threadIdx.x;
    if (e < E) {
        const int s = ei[e];
        const int d = ei[E + e];
        const unsigned pos = atomicAdd(cursor + d, 1u);
        esrc[pos] = s;
        edst[pos] = d;
    }
}

// ---------------- fused input net ----------------
__global__ void k_in(const float* __restrict__ x, const float* __restrict__ W1,
                     const float* __restrict__ b1, const float* __restrict__ g1,
                     const float* __restrict__ bn1, const float* __restrict__ W2,
                     const float* __restrict__ b2, const float* __restrict__ g2,
                     const float* __restrict__ bn2, float* __restrict__ C, int n) {
    __shared__ float As[64 * 132];
    __shared__ float Ws[4096];
    __shared__ float W1s[512];
    const int t = threadIdx.x;
    const int n0 = blockIdx.x * 64;
    if (t < 128) {
        W1s[t] = W1[t];
        W1s[128 + t] = W1[128 + t];
        W1s[256 + t] = W1[256 + t];
        W1s[384 + t] = W1[384 + t];
    }
    __syncthreads();
    {
        const int r = t >> 2, c0 = (t & 3) << 5;
        const int row = n0 + r;
        float4 xv = make_float4(0.f, 0.f, 0.f, 0.f);
        if (row < n) xv = *(const float4*)(x + (size_t)row * 4);
        float hv[32];
        float s = 0.f, q = 0.f;
#pragma unroll
        for (int j = 0; j < 32; ++j) {
            const int c = c0 + j;
            const float z = b1[c] + xv.x * W1s[c] + xv.y * W1s[128 + c] +
                            xv.z * W1s[256 + c] + xv.w * W1s[384 + c];
            hv[j] = z;
            s += z;
            q += z * z;
        }
        s += __shfl_xor(s, 1); s += __shfl_xor(s, 2);
        q += __shfl_xor(q, 1); q += __shfl_xor(q, 2);
        const float mean = s * 0.0078125f;
        const float var = q * 0.0078125f - mean * mean;
        const float rs = rsqrtf(var + 1e-5f);
#pragma unroll
        for (int j = 0; j < 32; ++j) {
            const int c = c0 + j;
            As[r * 132 + c] = geluf((hv[j] - mean) * rs * g1[c] + bn1[c]);
        }
    }
    float acc[4][8];
#pragma unroll
    for (int r = 0; r < 4; ++r)
#pragma unroll
        for (int o = 0; o < 8; ++o) acc[r][o] = 0.f;
    const int og = t & 15, eg = t >> 4;
    const int ogc = og << 2, r0 = eg << 2;
#pragma unroll
    for (int q4 = 0; q4 < 4; ++q4) {
        stage_wq(Ws, W2 + q4 * 4096, t);
        __syncthreads();
        kloop_q(As, Ws, acc, r0, ogc, q4 * 32);
        __syncthreads();
    }
    const float4 bA = *(const float4*)(b2 + ogc);
    const float4 bB = *(const float4*)(b2 + 64 + ogc);
    const float4 gA = *(const float4*)(g2 + ogc);
    const float4 gB = *(const float4*)(g2 + 64 + ogc);
    const float4 lA = *(const float4*)(bn2 + ogc);
    const float4 lB = *(const float4*)(bn2 + 64 + ogc);
#pragma unroll
    for (int r = 0; r < 4; ++r) {
        float v[8];
        v[0] = acc[r][0] + bA.x; v[1] = acc[r][1] + bA.y;
        v[2] = acc[r][2] + bA.z; v[3] = acc[r][3] + bA.w;
        v[4] = acc[r][4] + bB.x; v[5] = acc[r][5] + bB.y;
        v[6] = acc[r][6] + bB.z; v[7] = acc[r][7] + bB.w;
        float s = 0.f, q = 0.f;
#pragma unroll
        for (int o = 0; o < 8; ++o) { s += v[o]; q += v[o] * v[o]; }
#pragma unroll
        for (int m = 1; m < 16; m <<= 1) { s += __shfl_xor(s, m); q += __shfl_xor(q, m); }
        const float mean = s * 0.0078125f;
        const float var = q * 0.0078125f - mean * mean;
        const float rs = rsqrtf(var + 1e-5f);
        const int row = n0 + r0 + r;
        if (row < n) {
            *(float4*)(C + (size_t)row * 128 + ogc) = make_float4(
                (v[0] - mean) * rs * gA.x + lA.x, (v[1] - mean) * rs * gA.y + lA.y,
                (v[2] - mean) * rs * gA.z + lA.z, (v[3] - mean) * rs * gA.w + lA.w);
            *(float4*)(C + (size_t)row * 128 + 64 + ogc) = make_float4(
                (v[4] - mean) * rs * gB.x + lB.x, (v[5] - mean) * rs * gB.y + lB.y,
                (v[6] - mean) * rs * gB.z + lB.z, (v[7] - mean) * rs * gB.w + lB.w);
        }
    }
}

// ---------------- P & Q (+ fused residual update) ----------------
__global__ void k_pq(float* __restrict__ xcur, const float* __restrict__ upd,
                     const float* __restrict__ pbl, const float* __restrict__ g,
                     const float* __restrict__ b, const float* __restrict__ cW1,
                     const float* __restrict__ cb1, unsigned short* __restrict__ P,
                     unsigned short* __restrict__ Q, int n) {
    __shared__ float As[64 * 132];
    __shared__ float Ws[4096];
    __shared__ float sg[128], sb[128];
    const int t = threadIdx.x;
    const int n0 = blockIdx.x * 64;
    if (t < 128) { sg[t] = g[t]; sb[t] = b[t]; }
    __syncthreads();
    {
        const int r = t >> 2, c0 = (t & 3) << 5;
        const int row = n0 + r;
        const bool ok = row < n;
        float4 v4[8];
        float s = 0.f, q = 0.f;
        if (ok) {
#pragma unroll
            for (int j = 0; j < 8; ++j) {
                const int c = c0 + (j << 2);
                float4 xv = *(const float4*)(xcur + (size_t)row * 128 + c);
                if (upd) {
                    const float4 u = *(const float4*)(upd + (size_t)row * 128 + c);
                    const float4 pv = *(const float4*)(pbl + c);
                    xv = make_float4(xv.x + u.x + pv.x, xv.y + u.y + pv.y, xv.z + u.z + pv.z,
                                     xv.w + u.w + pv.w);
                    *(float4*)(xcur + (size_t)row * 128 + c) = xv;
                }
                v4[j] = xv;
                s += xv.x + xv.y + xv.z + xv.w;
                q += xv.x * xv.x + xv.y * xv.y + xv.z * xv.z + xv.w * xv.w;
            }
        } else {
#pragma unroll
            for (int j = 0; j < 8; ++j) v4[j] = make_float4(0.f, 0.f, 0.f, 0.f);
        }
        s += __shfl_xor(s, 1); s += __shfl_xor(s, 2);
        q += __shfl_xor(q, 1); q += __shfl_xor(q, 2);
        const float mean = s * 0.0078125f;
        const float var = q * 0.0078125f - mean * mean;
        const float rs = rsqrtf(var + 1e-5f);
#pragma unroll
        for (int j = 0; j < 8; ++j) {
            const int c = c0 + (j << 2);
            As[r * 132 + c + 0] = (v4[j].x - mean) * rs * sg[c + 0] + sb[c + 0];
            As[r * 132 + c + 1] = (v4[j].y - mean) * rs * sg[c + 1] + sb[c + 1];
            As[r * 132 + c + 2] = (v4[j].z - mean) * rs * sg[c + 2] + sb[c + 2];
            As[r * 132 + c + 3] = (v4[j].w - mean) * rs * sg[c + 3] + sb[c + 3];
        }
    }
    float accP[4][8], accQ[4][8];
#pragma unroll
    for (int r = 0; r < 4; ++r)
#pragma unroll
        for (int o = 0; o < 8; ++o) { accP[r][o] = 0.f; accQ[r][o] = 0.f; }
    const int og = t & 15, eg = t >> 4;
    const int ogc = og << 2, r0 = eg << 2;
#pragma unroll
    for (int q4 = 0; q4 < 4; ++q4) {
        stage_wq(Ws, cW1 + q4 * 4096, t);
        __syncthreads();
        kloop_q(As, Ws, accP, r0, ogc, q4 * 32);
        __syncthreads();
        stage_wq(Ws, cW1 + 16384 + q4 * 4096, t);
        __syncthreads();
        kloop_q(As, Ws, accQ, r0, ogc, q4 * 32);
        __syncthreads();
    }
    const float4 bA = *(const float4*)(cb1 + ogc);
    const float4 bB = *(const float4*)(cb1 + 64 + ogc);
#pragma unroll
    for (int r = 0; r < 4; ++r) {
        const int row = n0 + r0 + r;
        if (row < n) {
            ushort4 p0, p1, q0, q1;
            p0.x = bf16r(accP[r][0] - accQ[r][0] + bA.x);
            p0.y = bf16r(accP[r][1] - accQ[r][1] + bA.y);
            p0.z = bf16r(accP[r][2] - accQ[r][2] + bA.z);
            p0.w = bf16r(accP[r][3] - accQ[r][3] + bA.w);
            p1.x = bf16r(accP[r][4] - accQ[r][4] + bB.x);
            p1.y = bf16r(accP[r][5] - accQ[r][5] + bB.y);
            p1.z = bf16r(accP[r][6] - accQ[r][6] + bB.z);
            p1.w = bf16r(accP[r][7] - accQ[r][7] + bB.w);
            q0.x = bf16r(accQ[r][0]); q0.y = bf16r(accQ[r][1]);
            q0.z = bf16r(accQ[r][2]); q0.w = bf16r(accQ[r][3]);
            q1.x = bf16r(accQ[r][4]); q1.y = bf16r(accQ[r][5]);
            q1.z = bf16r(accQ[r][6]); q1.w = bf16r(accQ[r][7]);
            *(ushort4*)(P + (size_t)row * 128 + ogc) = p0;
            *(ushort4*)(P + (size_t)row * 128 + 64 + ogc) = p1;
            *(ushort4*)(Q + (size_t)row * 128 + ogc) = q0;
            *(ushort4*)(Q + (size_t)row * 128 + 64 + ogc) = q1;
        }
    }
}

// ---------------- fused edge conv + queued batch matvec -> upd ----------------
#define QN 16
__global__ __launch_bounds__(256, 2) void k_edge(
    const unsigned short* __restrict__ P, const unsigned short* __restrict__ Q,
    const int* __restrict__ esrc, const int* __restrict__ edst, const float* __restrict__ W2,
    const float* __restrict__ g1, const float* __restrict__ b1, const float* __restrict__ cb2,
    const float* __restrict__ g2, const float* __restrict__ b2,
    const unsigned* __restrict__ rowend, const unsigned* __restrict__ degc,
    const float* __restrict__ pW, float* __restrict__ upd, float* __restrict__ recmax,
    float* __restrict__ recsum, int* __restrict__ recid, int E) {
    __shared__ float Us[64 * 132];
    __shared__ float Ws[4096];
    __shared__ float Qq[QN * 260];  // queue: [amax(128) | amean(128)] per run, stride 260
    __shared__ int qnode[QN];
    __shared__ int sdst[64], ssrc[64], sdg[64];
    __shared__ float scb2[128], sg2[128], sb2[128];
    const int t = threadIdx.x;
    const int base = blockIdx.x * 512;
    if (t >= 128) {
        const int d = t - 128;
        scb2[d] = cb2[d];
        sg2[d] = g2[d];
        sb2[d] = b2[d];
    }
    const int lane = t & 63, wave = t >> 6;
    const int d0 = lane << 1;
    const float g1a = g1[d0], g1b = g1[d0 + 1], b1a = b1[d0], b1b = b1[d0 + 1];
    const int og = t & 15, eg = t >> 4;
    const int ogc = og << 2, r0 = eg << 2;
    int cur = -1, istart = 0;
    float vmax = -INFINITY, vsum = 0.f;
    int id0 = -1, id1 = -1;
    int qn = 0;  // uniform queue depth

    auto flushq = [&]() {
        if (qn == 0) return;
        __syncthreads();  // queue writes + qnode visible
        float qacc[8];
#pragma unroll
        for (int o = 0; o < 8; ++o) qacc[o] = 0.f;
        const int qr = t >> 4;        // row 0..15
        const int qc = (t & 15) << 3; // col 0..120 step 8
        for (int qs = 0; qs < 8; ++qs) {
            stage_wq(Ws, pW + qs * 4096, t);
            __syncthreads();
            const float* aq = Qq + qr * 260 + qs * 32;
#pragma unroll
            for (int kk = 0; kk < 32; ++kk) {
                const float av = aq[kk];
                const float* wr = Ws + kk * 128 + qc;
#pragma unroll
                for (int o = 0; o < 8; ++o) qacc[o] += av * wr[o];
            }
            __syncthreads();
        }
        if (qr < qn) {
            float* dstp = upd + (size_t)qnode[qr] * 128 + qc;
            *(float4*)(dstp) = make_float4(qacc[0], qacc[1], qacc[2], qacc[3]);
            *(float4*)(dstp + 4) = make_float4(qacc[4], qacc[5], qacc[6], qacc[7]);
        }
        __syncthreads();  // queue free for reuse
        qn = 0;
    };

    auto endrun = [&](int iend) {
        const unsigned re = rowend[cur];
        const unsigned dg = degc[cur];
        const unsigned rs0 = re - dg;
        const unsigned ps = (unsigned)(base + istart), pe = (unsigned)(base + iend);
        if (ps == rs0 && pe == re) {
            if (t < 128) {
                Qq[qn * 260 + t] = vmax;
                Qq[qn * 260 + 128 + t] = vsum / (float)dg;
            }
            if (t == 0) qnode[qn] = cur;
            ++qn;
            if (qn == QN) flushq();
        } else {
            const int slot = (istart == 0) ? 0 : 1;
            if (t < 128) {
                const size_t ro = (size_t)(2 * blockIdx.x + slot) * 128 + t;
                recmax[ro] = vmax;
                recsum[ro] = vsum;
            }
            if (slot == 0) id0 = cur; else id1 = cur;
        }
    };

    for (int s8 = 0; s8 < 8; ++s8) {
        const int sb = base + s8 * 64;
        __syncthreads();
        if (t < 64) {
            const int idx = sb + t;
            const int ci = idx < E ? idx : (E - 1);
            ssrc[t] = esrc[ci];
            const int d = edst[ci];
            sdg[t] = d;
            sdst[t] = (idx < E) ? d : -1;
        }
        __syncthreads();
        // Phase A: U rows = GELU(LN(P[dst]+Q[src])), bf16 gathers
#pragma unroll 4
        for (int p = 0; p < 16; ++p) {
            const int i = (p << 2) + wave;
            const unsigned pu = *(const unsigned*)(P + ((size_t)sdg[i] << 7) + d0);
            const unsigned qu = *(const unsigned*)(Q + ((size_t)ssrc[i] << 7) + d0);
            const float x0 = __uint_as_float(pu << 16) + __uint_as_float(qu << 16);
            const float x1 =
                __uint_as_float(pu & 0xffff0000u) + __uint_as_float(qu & 0xffff0000u);
            const float s = wred64(x0 + x1);
            const float q = wred64(x0 * x0 + x1 * x1);
            const float mean = s * 0.0078125f;
            const float var = q * 0.0078125f - mean * mean;
            const float rs = rsqrtf(var + 1e-5f);
            const float y0 = geluf((x0 - mean) * rs * g1a + b1a);
            const float y1 = geluf((x1 - mean) * rs * g1b + b1b);
            *(float2*)(Us + i * 132 + d0) = make_float2(y0, y1);
        }
        // Phase B: GEMM M2 = U @ cW2
        float acc[4][8];
#pragma unroll
        for (int r = 0; r < 4; ++r)
#pragma unroll
            for (int o = 0; o < 8; ++o) acc[r][o] = 0.f;
#pragma unroll
        for (int q4 = 0; q4 < 4; ++q4) {
            stage_wq(Ws, W2 + q4 * 4096, t);
            __syncthreads();
            kloop_q(Us, Ws, acc, r0, ogc, q4 * 32);
            __syncthreads();
        }
        // epilogue: +cb2, row LN over 16 lanes, GELU, write back to Us
#pragma unroll
        for (int r = 0; r < 4; ++r) {
            float v[8];
            float s = 0.f, q = 0.f;
#pragma unroll
            for (int o = 0; o < 8; ++o) {
                const int col = (o < 4) ? (ogc + o) : (64 + ogc + o - 4);
                v[o] = acc[r][o] + scb2[col];
                s += v[o];
                q += v[o] * v[o];
            }
#pragma unroll
            for (int m = 1; m < 16; m <<= 1) { s += __shfl_xor(s, m); q += __shfl_xor(q, m); }
            const float mean = s * 0.0078125f;
            const float var = q * 0.0078125f - mean * mean;
            const float rs = rsqrtf(var + 1e-5f);
#pragma unroll
            for (int o = 0; o < 8; ++o) {
                const int col = (o < 4) ? (ogc + o) : (64 + ogc + o - 4);
                v[o] = geluf((v[o] - mean) * rs * sg2[col] + sb2[col]);
            }
            *(float4*)(Us + (r0 + r) * 132 + ogc) = make_float4(v[0], v[1], v[2], v[3]);
            *(float4*)(Us + (r0 + r) * 132 + 64 + ogc) = make_float4(v[4], v[5], v[6], v[7]);
        }
        __syncthreads();
        // Phase C: run-length max/sum; complete runs -> queue (batched GEMM)
        for (int i = 0; i < 64; ++i) {
            const int dn = sdst[i];
            const int gi = s8 * 64 + i;
            if (dn != cur) {
                if (cur >= 0) endrun(gi);
                cur = dn;
                istart = gi;
                vmax = -INFINITY;
                vsum = 0.f;
            }
            if (dn >= 0 && t < 128) {
                const float v = Us[i * 132 + t];
                vmax = fmaxf(vmax, v);
                vsum += v;
            }
        }
    }
    if (cur >= 0) endrun(min(512, E - base));
    flushq();
    if (t == 0) {
        recid[2 * blockIdx.x] = id0;
        recid[2 * blockIdx.x + 1] = id1;
    }
}

// ---------------- merge boundary records + empty nodes -> upd ----------------
__global__ void k_merge2(const unsigned* __restrict__ rowend, const unsigned* __restrict__ degc,
                         const float* __restrict__ recmax, const float* __restrict__ recsum,
                         const int* __restrict__ recid, const float* __restrict__ pW,
                         float* __restrict__ upd, int n) {
    __shared__ float sm[128], ss[128];
    const int node = blockIdx.x;
    const int d = threadIdx.x;
    if (node >= n) return;
    const unsigned dg = degc[node];
    if (dg == 0u) {
        upd[(size_t)node * 128 + d] = 0.f;
        return;
    }
    const unsigned re = rowend[node], rs = re - dg;
    const int b0 = rs >> 9, b1 = (re - 1) >> 9;
    if (b0 == b1) return;
    float m = -INFINITY, s = 0.f;
    for (int b = b0; b <= b1; ++b) {
#pragma unroll
        for (int sl = 0; sl < 2; ++sl) {
            if (recid[2 * b + sl] == node) {
                const size_t ro = (size_t)(2 * b + sl) * 128 + d;
                m = fmaxf(m, recmax[ro]);
                s += recsum[ro];
            }
        }
    }
    sm[d] = m;
    ss[d] = s / (float)dg;
    __syncthreads();
    float a = 0.f;
#pragma unroll 8
    for (int k = 0; k < 128; ++k)
        a += sm[k] * pW[(size_t)k * 128 + d] + ss[k] * pW[(size_t)(128 + k) * 128 + d];
    upd[(size_t)node * 128 + d] = a;
}

// ---------------- fused final: x=xcur+upd+pb -> LN -> graph pooling ----------------
__global__ void k_lnpool(const float* __restrict__ xcur, const float* __restrict__ upd,
                         const float* __restrict__ pbl, const float* __restrict__ g,
                         const float* __restrict__ b, const int* __restrict__ batch,
                         unsigned* __restrict__ gmax, float* __restrict__ gsum,
                         unsigned* __restrict__ gcount, int n) {
    __shared__ float Ys[64 * 132];
    __shared__ int sbt[64];
    const int t = threadIdx.x;
    const int n0 = blockIdx.x * 64;
    if (t < 64) {
        const int node = n0 + t;
        sbt[t] = (node < n) ? batch[node] : -1;
    }
    {
        const int r = t >> 2, c0 = (t & 3) << 5;
        const int row = n0 + r;
        const bool ok = row < n;
        float4 v4[8];
        float s = 0.f, q = 0.f;
        if (ok) {
#pragma unroll
            for (int j = 0; j < 8; ++j) {
                const int c = c0 + (j << 2);
                const float4 xv = *(const float4*)(xcur + (size_t)row * 128 + c);
                const float4 u = *(const float4*)(upd + (size_t)row * 128 + c);
                const float4 pv = *(const float4*)(pbl + c);
                v4[j] = make_float4(xv.x + u.x + pv.x, xv.y + u.y + pv.y, xv.z + u.z + pv.z,
                                    xv.w + u.w + pv.w);
                s += v4[j].x + v4[j].y + v4[j].z + v4[j].w;
                q += v4[j].x * v4[j].x + v4[j].y * v4[j].y + v4[j].z * v4[j].z +
                     v4[j].w * v4[j].w;
            }
        } else {
#pragma unroll
            for (int j = 0; j < 8; ++j) v4[j] = make_float4(0.f, 0.f, 0.f, 0.f);
        }
        s += __shfl_xor(s, 1); s += __shfl_xor(s, 2);
        q += __shfl_xor(q, 1); q += __shfl_xor(q, 2);
        const float mean = s * 0.0078125f;
        const float var = q * 0.0078125f - mean * mean;
        const float rs = rsqrtf(var + 1e-5f);
#pragma unroll
        for (int j = 0; j < 8; ++j) {
            const int c = c0 + (j << 2);
            Ys[r * 132 + c + 0] = (v4[j].x - mean) * rs * g[c + 0] + b[c + 0];
            Ys[r * 132 + c + 1] = (v4[j].y - mean) * rs * g[c + 1] + b[c + 1];
            Ys[r * 132 + c + 2] = (v4[j].z - mean) * rs * g[c + 2] + b[c + 2];
            Ys[r * 132 + c + 3] = (v4[j].w - mean) * rs * g[c + 3] + b[c + 3];
        }
    }
    __syncthreads();
    if (t < 128) {
        int curg = -1;
        float vmax = -INFINITY, vsum = 0.f;
        unsigned cnt = 0;
        for (int i = 0; i < 64; ++i) {
            const int gid = sbt[i];
            if (gid != curg) {
                if (curg >= 0) {
                    atomicMax(gmax + (size_t)curg * 128 + t, fmap(vmax));
                    atomicAdd(gsum + (size_t)curg * 128 + t, vsum);
                    if (t == 0) atomicAdd(gcount + curg, cnt);
                }
                curg = gid;
                vmax = -INFINITY;
                vsum = 0.f;
                cnt = 0;
            }
            if (gid >= 0) {
                const float v = Ys[i * 132 + t];
                vmax = fmaxf(vmax, v);
                vsum += v;
                cnt++;
            }
        }
        if (curg >= 0) {
            atomicMax(gmax + (size_t)curg * 128 + t, fmap(vmax));
            atomicAdd(gsum + (size_t)curg * 128 + t, vsum);
            if (t == 0) atomicAdd(gcount + curg, cnt);
        }
    }
}

// ---------------- graph pooling (input stage) ----------------
__global__ void k_pool_init(unsigned* __restrict__ gmax1, float* __restrict__ gsum1,
                            unsigned* __restrict__ gcount1, unsigned* __restrict__ gmax2,
                            float* __restrict__ gsum2, unsigned* __restrict__ gcount2, int ng) {
    const int i = blockIdx.x * 256 + threadIdx.x;
    if (i < ng * 128) {
        gmax1[i] = MAPNEGINF;
        gsum1[i] = 0.f;
        gmax2[i] = MAPNEGINF;
        gsum2[i] = 0.f;
    }
    if (i < ng) {
        gcount1[i] = 0u;
        gcount2[i] = 0u;
    }
}

__global__ void k_pool(const float* __restrict__ in, const int* __restrict__ batch,
                       unsigned* __restrict__ gmax, float* __restrict__ gsum,
                       unsigned* __restrict__ gcount, int n) {
    const int t = threadIdx.x;
    if (t >= 128) return;
    const int per = (n + gridDim.x - 1) / gridDim.x;
    const int i0 = blockIdx.x * per;
    const int i1 = min(n, i0 + per);
    if (i0 >= i1) return;
    int cur = batch[i0];
    float vmax = -INFINITY, vsum = 0.f;
    unsigned cnt = 0;
    for (int i = i0; i < i1; ++i) {
        const int g = batch[i];
        if (g != cur) {
            atomicMax(gmax + (size_t)cur * 128 + t, fmap(vmax));
            atomicAdd(gsum + (size_t)cur * 128 + t, vsum);
            if (t == 0) atomicAdd(gcount + cur, cnt);
            cur = g;
            vmax = -INFINITY;
            vsum = 0.f;
            cnt = 0;
        }
        const float v = in[(size_t)i * 128 + t];
        vmax = fmaxf(vmax, v);
        vsum += v;
        cnt++;
    }
    atomicMax(gmax + (size_t)cur * 128 + t, fmap(vmax));
    atomicAdd(gsum + (size_t)cur * 128 + t, vsum);
    if (t == 0) atomicAdd(gcount + cur, cnt);
}

__global__ void k_xp(const unsigned* __restrict__ gmax1, const float* __restrict__ gsum1,
                     const unsigned* __restrict__ gcount1, const unsigned* __restrict__ gmax2,
                     const float* __restrict__ gsum2, const unsigned* __restrict__ gcount2,
                     float* __restrict__ xp) {
    const int g = blockIdx.x, d = threadIdx.x;
    const unsigned c1u = gcount1[g], c2u = gcount2[g];
    const float c1 = (float)(c1u < 1u ? 1u : c1u);
    const float c2 = (float)(c2u < 1u ? 1u : c2u);
    const unsigned m1 = gmax1[g * 128 + d], m2 = gmax2[g * 128 + d];
    xp[g * 512 + d] = (m1 == MAPNEGINF) ? 0.f : funmap(m1);
    xp[g * 512 + 128 + d] = gsum1[g * 128 + d] / c1;
    xp[g * 512 + 256 + d] = (m2 == MAPNEGINF) ? 0.f : funmap(m2);
    xp[g * 512 + 384 + d] = gsum2[g * 128 + d] / c2;
}

// ---------------- knowledge MLP (tiny) ----------------
__global__ __launch_bounds__(64) void k_know(
    const float* __restrict__ xp, const float* __restrict__ kW1, const float* __restrict__ kb1,
    const float* __restrict__ kg1, const float* __restrict__ kbb1, const float* __restrict__ kW2,
    const float* __restrict__ kb2, const float* __restrict__ kg2, const float* __restrict__ kbb2,
    const float* __restrict__ kW3, const float* __restrict__ kb3, const float* __restrict__ kg3,
    const float* __restrict__ kbb3, const float* __restrict__ kW4, const float* __restrict__ kb4,
    float* __restrict__ out) {
    __shared__ float sh[512];
    __shared__ float s3[32];
    const int l = threadIdx.x, g = blockIdx.x;
    const int d0 = l << 1;
    *(float4*)(sh + l * 8) = *(const float4*)(xp + g * 512 + l * 8);
    *(float4*)(sh + l * 8 + 4) = *(const float4*)(xp + g * 512 + l * 8 + 4);
    __syncthreads();
    float a0 = kb1[d0], a1 = kb1[d0 + 1];
    for (int k = 0; k < 512; ++k) {
        const float u = sh[k];
        const float2 w = *(const float2*)(kW1 + k * 128 + d0);
        a0 += u * w.x;
        a1 += u * w.y;
    }
    {
        const float s = wred64(a0 + a1), q = wred64(a0 * a0 + a1 * a1);
        const float mean = s * 0.0078125f, var = q * 0.0078125f - mean * mean;
        const float rs = rsqrtf(var + 1e-5f);
        a0 = geluf((a0 - mean) * rs * kg1[d0] + kbb1[d0]);
        a1 = geluf((a1 - mean) * rs * kg1[d0 + 1] + kbb1[d0 + 1]);
    }
    __syncthreads();
    sh[d0] = a0;
    sh[d0 + 1] = a1;
    __syncthreads();
    float b0v = kb2[d0], b1v = kb2[d0 + 1];
    for (int k = 0; k < 128; ++k) {
        const float u = sh[k];
        const float2 w = *(const float2*)(kW2 + k * 128 + d0);
        b0v += u * w.x;
        b1v += u * w.y;
    }
    {
        const float s = wred64(b0v + b1v), q = wred64(b0v * b0v + b1v * b1v);
        const float mean = s * 0.0078125f, var = q * 0.0078125f - mean * mean;
        const float rs = rsqrtf(var + 1e-5f);
        b0v = geluf((b0v - mean) * rs * kg2[d0] + kbb2[d0]);
        b1v = geluf((b1v - mean) * rs * kg2[d0 + 1] + kbb2[d0 + 1]);
    }
    __syncthreads();
    sh[d0] = b0v;
    sh[d0 + 1] = b1v;
    __syncthreads();
    const int d3 = (l & 15) << 1;
    float c0 = kb3[d3], c1 = kb3[d3 + 1];
    for (int k = 0; k < 128; ++k) {
        const float u = sh[k];
        const float2 w = *(const float2*)(kW3 + k * 32 + d3);
        c0 += u * w.x;
        c1 += u * w.y;
    }
    {
        float s = c0 + c1, q = c0 * c0 + c1 * c1;
#pragma unroll
        for (int m = 1; m < 16; m <<= 1) {
            s += __shfl_xor(s, m);
            q += __shfl_xor(q, m);
        }
        const float mean = s * 0.03125f, var = q * 0.03125f - mean * mean;
        const float rs = rsqrtf(var + 1e-5f);
        c0 = geluf((c0 - mean) * rs * kg3[d3] + kbb3[d3]);
        c1 = geluf((c1 - mean) * rs * kg3[d3 + 1] + kbb3[d3 + 1]);
    }
    if (l < 16) {
        s3[d3] = c0;
        s3[d3 + 1] = c1;
    }
    __syncthreads();
    if (l == 0) {
        float rr = kb4[0];
        for (int k = 0; k < 32; ++k) rr += s3[k] * kW4[k];
        out[g] = rr;
    }
}

// ---------------- host launch ----------------
extern "C" void kernel_launch(void* const* d_in, const int* in_sizes, int n_in, void* d_out,
                              int out_size, void* d_ws, size_t ws_size, hipStream_t stream) {
    const int N = in_sizes[0] / 4;
    const int E = in_sizes[1] / 2;
    const int G = 64;
    const int L = 4;

    const float* x = (const float*)d_in[0];
    const int* ei = (const int*)d_in[1];
    const int* batch = (const int*)d_in[2];
    const float* inW1 = (const float*)d_in[4];
    const float* inb1 = (const float*)d_in[5];
    const float* ing1 = (const float*)d_in[6];
    const float* inbn1 = (const float*)d_in[7];
    const float* inW2 = (const float*)d_in[8];
    const float* inb2 = (const float*)d_in[9];
    const float* ing2 = (const float*)d_in[10];
    const float* inbn2 = (const float*)d_in[11];
    const float* pre_g = (const float*)d_in[12];
    const float* pre_b = (const float*)d_in[13];
    const float* cW1 = (const float*)d_in[14];
    const float* cb1 = (const float*)d_in[15];
    const float* cg1 = (const float*)d_in[16];
    const float* cbb1 = (const float*)d_in[17];
    const float* cW2 = (const float*)d_in[18];
    const float* cb2 = (const float*)d_in[19];
    const float* cg2 = (const float*)d_in[20];
    const float* cbb2 = (const float*)d_in[21];
    const float* pW = (const float*)d_in[22];
    const float* pb = (const float*)d_in[23];
    const float* ag_g = (const float*)d_in[24];
    const float* ag_b = (const float*)d_in[25];
    const float* kW1 = (const float*)d_in[26];
    const float* kb1 = (const float*)d_in[27];
    const float* kg1 = (const float*)d_in[28];
    const float* kbb1 = (const float*)d_in[29];
    const float* kW2 = (const float*)d_in[30];
    const float* kb2 = (const float*)d_in[31];
    const float* kg2 = (const float*)d_in[32];
    const float* kbb2 = (const float*)d_in[33];
    const float* kW3 = (const float*)d_in[34];
    const float* kb3 = (const float*)d_in[35];
    const float* kg3 = (const float*)d_in[36];
    const float* kbb3 = (const float*)d_in[37];
    const float* kW4 = (const float*)d_in[38];
    const float* kb4 = (const float*)d_in[39];
    float* out = (float*)d_out;

    const int nblkE = (E + 511) / 512;

    char* wsb = (char*)d_ws;
    size_t off = 0;
    auto ALC = [&](size_t bytes) {
        void* p = wsb + off;
        off = (off + bytes + 255) & ~(size_t)255;
        return p;
    };
    const size_t NB = (size_t)N * 128 * 4;
    float* xcur = (float*)ALC(NB);
    float* upd = (float*)ALC(NB);
    unsigned short* Pb = (unsigned short*)ALC((size_t)N * 128 * 2);
    unsigned short* Qb = (unsigned short*)ALC((size_t)N * 128 * 2);
    unsigned* deg = (unsigned*)ALC((size_t)N * 4);
    unsigned* cursor = (unsigned*)ALC((size_t)N * 4);
    unsigned* degc = (unsigned*)ALC((size_t)N * 4);
    unsigned* rowend = (unsigned*)ALC((size_t)N * 4);
    unsigned* bsum = (unsigned*)ALC(4096);
    int* esrc = (int*)ALC((size_t)E * 4);
    int* edst = (int*)ALC((size_t)E * 4);
    float* recmax = (float*)ALC((size_t)nblkE * 2 * 128 * 4);
    float* recsum = (float*)ALC((size_t)nblkE * 2 * 128 * 4);
    int* recid = (int*)ALC((size_t)nblkE * 2 * 4);
    unsigned* gmax1 = (unsigned*)ALC((size_t)G * 128 * 4);
    float* gsum1 = (float*)ALC((size_t)G * 128 * 4);
    unsigned* gcount1 = (unsigned*)ALC((size_t)G * 4);
    unsigned* gmax2 = (unsigned*)ALC((size_t)G * 128 * 4);
    float* gsum2 = (float*)ALC((size_t)G * 128 * 4);
    unsigned* gcount2 = (unsigned*)ALC((size_t)G * 4);
    float* xp = (float*)ALC((size_t)G * 512 * 4);

    if (off > ws_size) {
        k_zero<<<(out_size + 255) / 256, 256, 0, stream>>>((unsigned*)d_out, out_size);
        return;
    }

    // --- CSR-style dst-sorted edge arrays ---
    k_zero<<<(N + 255) / 256, 256, 0, stream>>>(deg, N);
    k_count<<<(E + 255) / 256, 256, 0, stream>>>(ei, deg, E);
    const int nb = (N + 1023) / 1024;
    k_scan1<<<nb, 256, 0, stream>>>(deg, cursor, bsum, N);
    k_scan2<<<1, 256, 0, stream>>>(bsum, nb);
    k_scan3<<<nb, 256, 0, stream>>>(cursor, bsum, N);
    k_scatter<<<(E + 255) / 256, 256, 0, stream>>>(ei, cursor, esrc, edst, E);
    k_copyu<<<(N + 255) / 256, 256, 0, stream>>>(deg, cursor, degc, rowend, N);

    // --- input net + first pooling ---
    const int grid64 = (N + 63) / 64;
    k_in<<<grid64, 256, 0, stream>>>(x, inW1, inb1, ing1, inbn1, inW2, inb2, ing2, inbn2, xcur,
                                     N);
    k_pool_init<<<(G * 128 + 255) / 256, 256, 0, stream>>>(gmax1, gsum1, gcount1, gmax2, gsum2,
                                                           gcount2, G);
    k_pool<<<512, 256, 0, stream>>>(xcur, batch, gmax1, gsum1, gcount1, N);

    // --- edge conv layers ---
    for (int l = 0; l < L; ++l) {
        k_pq<<<grid64, 256, 0, stream>>>(xcur, (l == 0) ? (const float*)nullptr : upd,
                                         (l == 0) ? (const float*)nullptr : (pb + (l - 1) * 128),
                                         pre_g + l * 128, pre_b + l * 128,
                                         cW1 + (size_t)l * 32768, cb1 + l * 128, Pb, Qb, N);
        k_edge<<<nblkE, 256, 0, stream>>>(Pb, Qb, esrc, edst, cW2 + (size_t)l * 16384,
                                          cg1 + l * 128, cbb1 + l * 128, cb2 + l * 128,
                                          cg2 + l * 128, cbb2 + l * 128, rowend, degc,
                                          pW + (size_t)l * 32768, upd, recmax, recsum, recid, E);
        k_merge2<<<N, 128, 0, stream>>>(rowend, degc, recmax, recsum, recid,
                                        pW + (size_t)l * 32768, upd, N);
    }

    // --- fused final LN + pooling, then head ---
    k_lnpool<<<grid64, 256, 0, stream>>>(xcur, upd, pb + 3 * 128, ag_g, ag_b, batch, gmax2,
                                         gsum2, gcount2, N);
    k_xp<<<G, 128, 0, stream>>>(gmax1, gsum1, gcount1, gmax2, gsum2, gcount2, xp);
    k_know<<<G, 64, 0, stream>>>(xp, kW1, kb1, kg1, kbb1, kW2, kb2, kg2, kbb2, kW3, kb3, kg3,
                                 kbb3, kW4, kb4, out);
}